// Round 6
// baseline (25225.702 us; speedup 1.0000x reference)
//
#include <hip/hip_runtime.h>
#include <stdint.h>

typedef __bf16 bf16x8 __attribute__((ext_vector_type(8)));
typedef float f32x4 __attribute__((ext_vector_type(4)));
typedef unsigned long long u64;

#define BB 64
#define TT 2048
#define DD 320
#define HH 256
#define NC 10
#define GH 1024  // 4*H

#define GB 4         // batch groups (16 batches each)
#define GJ 4         // j-slice WGs per group (64 hidden units each)
#define MB 16        // batches per group
#define JW 64        // hidden units per WG
#define NTHREADS 512 // 8 waves
#define ROWS (MB * HH)   // shorts per parity row-block (4096)
#define NWG_LAUNCH 64    // 8 blocks per XCD under round-robin dispatch; b%8>=4 exit
#define HSROUNDS 3
#define HSSPIN 256
#define POLL_GUARD 2000000

__device__ __forceinline__ unsigned short f2bf(float f) {
  unsigned u = __float_as_uint(f);
  u += 0x7FFF + ((u >> 16) & 1);  // RNE
  return (unsigned short)(u >> 16);
}

__global__ void convert_bf16_k(const float* __restrict__ src,
                               unsigned short* __restrict__ dst, int n) {
  int i = blockIdx.x * blockDim.x + threadIdx.x;
  int st = gridDim.x * blockDim.x;
  for (; i < n; i += st) dst[i] = f2bf(src[i]);
}

__global__ void bias_sum_k(const float* __restrict__ a, const float* __restrict__ b,
                           float* __restrict__ d, int n) {
  int i = blockIdx.x * blockDim.x + threadIdx.x;
  if (i < n) d[i] = a[i] + b[i];
}

__global__ void zero_claim_k(int* p) { p[threadIdx.x] = 0; }

__device__ __forceinline__ float sigm(float x) { return 1.f / (1.f + __expf(-x)); }
__device__ __forceinline__ float tanh_s(float x) { return 2.f * sigm(2.f * x) - 1.f; }

__device__ __forceinline__ u64 ald(const u64* p) {
  return __hip_atomic_load(p, __ATOMIC_RELAXED, __HIP_MEMORY_SCOPE_AGENT);
}
__device__ __forceinline__ void ast(u64* p, u64 v) {
  __hip_atomic_store(p, v, __ATOMIC_RELAXED, __HIP_MEMORY_SCOPE_AGENT);
}

// ---- XCD-local (same-L2) path (R5-proven st_wt/sc0 coherence) ------------
__device__ __forceinline__ void st_wt(u64* p, u64 v) {
  asm volatile("global_store_dwordx2 %0, %1, off" : : "v"(p), "v"(v) : "memory");
}
__device__ __forceinline__ u64 ld1_sc0(const u64* p) {
  u64 v;
  asm volatile("global_load_dwordx2 %0, %1, off sc0\n\t"
               "s_waitcnt vmcnt(0)"
               : "=&v"(v) : "v"(p) : "memory");
  __builtin_amdgcn_sched_barrier(0);
  return v;
}
__device__ __forceinline__ void vm_wait0() {
  asm volatile("s_waitcnt vmcnt(0)" ::: "memory");
  __builtin_amdgcn_sched_barrier(0);  // rule #18: pin uses after the wait
}
// 16B A-fragment load. local: sc0 issue (caller does vm_wait0 before use).
// fallback: agent-scope 2x8B, completes inline.
__device__ __forceinline__ void ldfrag(bool local, const unsigned short* p, f32x4& d) {
  if (local) {
    asm volatile("global_load_dwordx4 %0, %1, off sc0" : "=&v"(d) : "v"(p) : "memory");
  } else {
    union { u64 q[2]; f32x4 v; } u;
    u.q[0] = ald((const u64*)p);
    u.q[1] = ald(((const u64*)p) + 1);
    d = u.v;
  }
}
__device__ __forceinline__ void st32w(bool local, unsigned* p, unsigned v) {
  if (local) asm volatile("global_store_dword %0, %1, off" : : "v"(p), "v"(v) : "memory");
  else __hip_atomic_store(p, v, __ATOMIC_RELAXED, __HIP_MEMORY_SCOPE_AGENT);
}

// R7-verified in-register 4x4 transpose among each 4-lane cluster.
__device__ __forceinline__ void xpose4(f32x4& v, int ln) {
  const bool b0 = (ln & 1) != 0;
  const bool b1 = (ln & 2) != 0;
  float x0 = __shfl_xor((float)v[0], 1);
  float x1 = __shfl_xor((float)v[1], 1);
  float x2 = __shfl_xor((float)v[2], 1);
  float x3 = __shfl_xor((float)v[3], 1);
  f32x4 u;
  u[0] = b0 ? x1 : v[0];
  u[1] = b0 ? v[1] : x0;
  u[2] = b0 ? x3 : v[2];
  u[3] = b0 ? v[3] : x2;
  float y0 = __shfl_xor((float)u[0], 2);
  float y1 = __shfl_xor((float)u[1], 2);
  float y2 = __shfl_xor((float)u[2], 2);
  float y3 = __shfl_xor((float)u[3], 2);
  v[0] = b1 ? y2 : u[0];
  v[1] = b1 ? y3 : u[1];
  v[2] = b1 ? u[2] : y0;
  v[3] = b1 ? u[3] : y1;
}

// R9: persistent fused 2-layer LSTM, flag-based raw-row exchange.
// h published as bf16 rows [16 batches][256 units] (parity-2 within layer,
// full-T depth for L0->L1). Producer: data stores -> vmcnt(0) -> per-wave
// flag=t+1. Consumer: ballot-poll flags, then A-fragments load DIRECTLY
// from L2 into registers. No LDS, no barriers, no tags in the main loop.
// R8 BUG FIXED: flags are now [GJ][8] per (group,layer) = 32 words — R8
// had 4 WGs colliding on 8 words, so a flag could read t+1 while 3 of the
// 4 WGs' row slices were still stale (the 6.1e-3 absmax signature).
// Parity safety: producer passes its step-t wait only when all 32 waves of
// the layer flagged >= t, which implies every consumer finished step-(t-1)
// loads of the parity slot about to be overwritten (2-phase bound).
template <int KCX, bool IS_L0>
__device__ __forceinline__ void lstm_role(
    const unsigned short* __restrict__ xin,  // L0: x bf16 [B][T][KCX*32]
    unsigned short* __restrict__ h1g,        // [TT][16][256] shorts (this group)
    const unsigned short* __restrict__ Wih,
    const unsigned short* __restrict__ Whh,
    const float* __restrict__ bias,
    float* __restrict__ hlast,               // L1: [B][HH] f32
    unsigned short* __restrict__ hxl,        // [2][16][256] shorts (gb,layer)
    u64* __restrict__ flS,                   // [32] own-layer (gj,wave) flags
    u64* __restrict__ flX,                   // L1: L0 (gj,wave) flags [32]
    int gb, int gj, bool local)
{
  constexpr int KX = KCX * 32;
  constexpr int KCH = HH / 32;  // 8

  const int tid = threadIdx.x;
  const int wv = tid >> 6;
  const int ln = tid & 63;
  const int lm = ln & 15;
  const int lq = ln >> 4;
  const int j0 = gj * JW;
  const int b0 = gb * MB;

  // ---- weights -> registers (once), gate-quad permuted rows (R7) ----
  bf16x8 bW[2][KCX + KCH];
  float bsv[2];
#pragma unroll
  for (int i = 0; i < 2; ++i) {
    int grow = (lm & 3) * HH + j0 + wv * 8 + ((lm >> 2) << 1) + i;
#pragma unroll
    for (int kc = 0; kc < KCX; ++kc)
      bW[i][kc] = *(const bf16x8*)&Wih[(size_t)grow * KX + kc * 32 + lq * 8];
#pragma unroll
    for (int kc = 0; kc < KCH; ++kc)
      bW[i][KCX + kc] = *(const bf16x8*)&Whh[(size_t)grow * HH + kc * 32 + lq * 8];
    bsv[i] = bias[grow];
  }

  const int pbatch = lq * 4 + (lm & 3);                   // batch in group
  const int uoff = j0 + wv * 8 + ((lm >> 2) << 1);        // unit index of h0
  float c0 = 0.f, c1 = 0.f;

  // ---- preamble: xf prefetch for t=0 (L0) ----
  f32x4 xfq[IS_L0 ? KCX : 1];
  if (IS_L0) {
#pragma unroll
    for (int kc = 0; kc < KCX; ++kc)
      ldfrag(local, &xin[((size_t)(b0 + lm) * TT + 0) * KX + kc * 32 + lq * 8], xfq[kc]);
  }

#pragma unroll 1
  for (int t = 0; t < TT; ++t) {
    // ---- flag wait (ballot over per-lane flag loads, 32 flags/stream) ----
    {
      const u64* fp; u64 thr;
      if (IS_L0) { fp = &flS[ln & 31]; thr = (u64)t; }
      else if (ln < 32) { fp = &flS[ln]; thr = (u64)t; }          // parity safety
      else { fp = &flX[ln & 31]; thr = (u64)(t + 1); }            // h1(t) ready
      int g = 0;
      for (;;) {
        u64 v = local ? ld1_sc0(fp) : ald(fp);
        if (__ballot(v >= thr) == ~0ull) break;
        if (++g > POLL_GUARD) break;  // fail visibly (absmax) instead of hang
      }
    }

    const unsigned short* hxc = hxl + (size_t)((t + 1) & 1) * ROWS;  // h(t-1)
    f32x4 hfq[KCH];
    f32x4 xrq[IS_L0 ? 1 : KCX];
    if (!IS_L0) {
#pragma unroll
      for (int kc = 0; kc < KCX; ++kc)
        ldfrag(local, &h1g[((size_t)t * MB + lm) * HH + kc * 32 + lq * 8], xrq[kc]);
    }
    if (t > 0) {
#pragma unroll
      for (int kc = 0; kc < KCH; ++kc)
        ldfrag(local, &hxc[lm * HH + kc * 32 + lq * 8], hfq[kc]);
    }

    f32x4 ac[2][2] = {{{0.f, 0.f, 0.f, 0.f}, {0.f, 0.f, 0.f, 0.f}},
                      {{0.f, 0.f, 0.f, 0.f}, {0.f, 0.f, 0.f, 0.f}}};
    if (IS_L0) {
      // x-part from prefetched regs — fills the h-load shadow
#pragma unroll
      for (int kc = 0; kc < KCX; ++kc) {
        bf16x8 a = __builtin_bit_cast(bf16x8, xfq[kc]);
        ac[0][kc & 1] = __builtin_amdgcn_mfma_f32_16x16x32_bf16(a, bW[0][kc], ac[0][kc & 1], 0, 0, 0);
        ac[1][kc & 1] = __builtin_amdgcn_mfma_f32_16x16x32_bf16(a, bW[1][kc], ac[1][kc & 1], 0, 0, 0);
      }
      if (t > 0 && local) vm_wait0();
    } else {
      if (local) vm_wait0();  // covers xrq + hfq
#pragma unroll
      for (int kc = 0; kc < KCX; ++kc) {
        bf16x8 a = __builtin_bit_cast(bf16x8, xrq[kc]);
        ac[0][kc & 1] = __builtin_amdgcn_mfma_f32_16x16x32_bf16(a, bW[0][kc], ac[0][kc & 1], 0, 0, 0);
        ac[1][kc & 1] = __builtin_amdgcn_mfma_f32_16x16x32_bf16(a, bW[1][kc], ac[1][kc & 1], 0, 0, 0);
      }
    }
    if (t > 0) {
#pragma unroll
      for (int kc = 0; kc < KCH; ++kc) {
        bf16x8 a = __builtin_bit_cast(bf16x8, hfq[kc]);
        ac[0][kc & 1] = __builtin_amdgcn_mfma_f32_16x16x32_bf16(a, bW[0][KCX + kc], ac[0][kc & 1], 0, 0, 0);
        ac[1][kc & 1] = __builtin_amdgcn_mfma_f32_16x16x32_bf16(a, bW[1][KCX + kc], ac[1][kc & 1], 0, 0, 0);
      }
    }

    // ---- gate quad regroup in-register (R7-verified) ----
    f32x4 A0 = ac[0][0] + ac[0][1];
    f32x4 A1 = ac[1][0] + ac[1][1];
    A0[0] += bsv[0]; A0[1] += bsv[0]; A0[2] += bsv[0]; A0[3] += bsv[0];
    A1[0] += bsv[1]; A1[1] += bsv[1]; A1[2] += bsv[1]; A1[3] += bsv[1];
    xpose4(A0, ln);  // slots = i,f,g,o of unit uoff   for batch pbatch
    xpose4(A1, ln);  // slots = i,f,g,o of unit uoff+1

    c0 = sigm(A0[1]) * c0 + sigm(A0[0]) * tanh_s(A0[2]);
    c1 = sigm(A1[1]) * c1 + sigm(A1[0]) * tanh_s(A1[2]);
    float h0 = sigm(A0[3]) * tanh_s(c0);
    float h1 = sigm(A1[3]) * tanh_s(c1);
    unsigned pair = (unsigned)f2bf(h0) | ((unsigned)f2bf(h1) << 16);

    // ---- publish raw rows (16B contiguous per row per wave), then flag ----
    unsigned short* hxn = hxl + (size_t)(t & 1) * ROWS;
    st32w(local, (unsigned*)&hxn[pbatch * HH + uoff], pair);
    if (IS_L0) {
      st32w(local, (unsigned*)&h1g[((size_t)t * MB + pbatch) * HH + uoff], pair);
    } else if (t == TT - 1) {
      hlast[(size_t)(b0 + pbatch) * HH + uoff] = h0;
      hlast[(size_t)(b0 + pbatch) * HH + uoff + 1] = h1;
    }
    vm_wait0();  // data in L2/MALL before flag issues
    if (ln == 0) {
      u64* fw = &flS[gj * 8 + wv];   // R9: per-(WG,wave) slot — no collision
      if (local) st_wt(fw, (u64)(t + 1));
      else ast(fw, (u64)(t + 1));
    }

    // ---- xf prefetch for t+1 (drained by next poll's vmcnt(0)) ----
    if (IS_L0 && t + 1 < TT) {
#pragma unroll
      for (int kc = 0; kc < KCX; ++kc)
        ldfrag(local, &xin[((size_t)(b0 + lm) * TT + (t + 1)) * KX + kc * 32 + lq * 8], xfq[kc]);
    }
  }
}

__launch_bounds__(NTHREADS, 1)
__global__ void lstm_fused(const unsigned short* __restrict__ xb,
                           unsigned short* __restrict__ h1buf,
                           const unsigned short* __restrict__ Wih0,
                           const unsigned short* __restrict__ Whh0,
                           const float* __restrict__ bias0,
                           const unsigned short* __restrict__ Wih1,
                           const unsigned short* __restrict__ Whh1,
                           const float* __restrict__ bias1,
                           float* __restrict__ h2last,
                           unsigned short* __restrict__ hxrow,
                           int* __restrict__ claim) {
  __shared__ int sCtl[2];

  // Static mapping: round-robin dispatch puts the 8 blocks of group g
  // (blockIdx%8==g) on one XCD; the handshake verifies functionally.
  const int gb = (int)blockIdx.x & 7;
  const int sub = (int)blockIdx.x >> 3;
  if (gb >= GB) return;  // spare blocks on XCDs 4..7 exit immediately

  if (threadIdx.x == 0) {
    u64* hs = (u64*)claim;                   // [32] tokens   (bytes 0..255)
    unsigned* vd = (unsigned*)(claim + 64);  // [32] verdicts (bytes 256..383)
    const int gid = gb * 8 + sub;
    bool lok = true;
    for (int r = 0; r < HSROUNDS && lok; ++r) {
      st_wt(&hs[gid], ((u64)(0xC0DE0000u + (unsigned)r) << 32) | (unsigned)gid);
      int it = 0;
      bool all;
      do {
        all = true;
        for (int m = 0; m < 8; ++m) {
          u64 v = ld1_sc0(&hs[gb * 8 + m]);
          unsigned hv = (unsigned)(v >> 32) - 0xC0DE0000u;
          all &= (hv >= (unsigned)r && hv < (unsigned)HSROUNDS);
        }
      } while (!all && ++it < HSSPIN);
      lok &= all;
    }
    __hip_atomic_store(&vd[gid], lok ? 2u : 1u, __ATOMIC_RELAXED,
                       __HIP_MEMORY_SCOPE_AGENT);
    bool ul = true;
    for (int m = 0; m < 8; ++m) {
      unsigned v;
      do {
        v = __hip_atomic_load(&vd[gb * 8 + m], __ATOMIC_RELAXED,
                              __HIP_MEMORY_SCOPE_AGENT);
      } while (v == 0);
      ul &= (v == 2);
    }
    sCtl[0] = ul ? 1 : 0;
  }
  __syncthreads();
  const bool local = sCtl[0] != 0;

  const int role = sub >> 2;
  const int gj = sub & 3;
  // flags: bytes 512.. : [GB][2][32] u64 = 2048 B
  u64* fl = (u64*)(claim + 128);
  unsigned short* h1g = h1buf + (size_t)gb * TT * ROWS;
  if (role == 0)
    lstm_role<DD / 32, true>(xb, h1g, Wih0, Whh0, bias0, nullptr,
                             hxrow + ((size_t)gb * 2 + 0) * 2 * ROWS,
                             fl + (gb * 2 + 0) * 32, nullptr, gb, gj, local);
  else
    lstm_role<HH / 32, false>(nullptr, h1g, Wih1, Whh1, bias1, h2last,
                              hxrow + ((size_t)gb * 2 + 1) * 2 * ROWS,
                              fl + (gb * 2 + 1) * 32, fl + (gb * 2 + 0) * 32,
                              gb, gj, local);
}

__global__ void fc_k(const float* __restrict__ h, const float* __restrict__ W,
                     const float* __restrict__ b, float* __restrict__ out) {
  int tid = threadIdx.x;
  if (tid < BB * NC) {
    int bb = tid / NC, cc = tid % NC;
    float s = b[cc];
    for (int j = 0; j < HH; ++j) s += h[bb * HH + j] * W[cc * HH + j];
    out[tid] = s;
  }
}

extern "C" void kernel_launch(void* const* d_in, const int* in_sizes, int n_in,
                              void* d_out, int out_size, void* d_ws, size_t ws_size,
                              hipStream_t stream) {
  (void)in_sizes; (void)n_in; (void)out_size;
  const float* x    = (const float*)d_in[0];
  const float* Wih0 = (const float*)d_in[1];
  const float* Whh0 = (const float*)d_in[2];
  const float* bih0 = (const float*)d_in[3];
  const float* bhh0 = (const float*)d_in[4];
  const float* Wih1 = (const float*)d_in[5];
  const float* Whh1 = (const float*)d_in[6];
  const float* bih1 = (const float*)d_in[7];
  const float* bhh1 = (const float*)d_in[8];
  const float* Wfc  = (const float*)d_in[9];
  const float* bfc  = (const float*)d_in[10];

  char* p = (char*)d_ws;
  size_t off = 0;
  auto alloc = [&](size_t bytes) -> char* {
    char* q = p + off;
    off += (bytes + 255) & ~(size_t)255;
    return q;
  };
  float* bias0 = (float*)alloc(GH * 4);
  float* bias1 = (float*)alloc(GH * 4);
  unsigned short* Wih0b = (unsigned short*)alloc((size_t)GH * DD * 2);
  unsigned short* Whh0b = (unsigned short*)alloc((size_t)GH * HH * 2);
  unsigned short* Wih1b = (unsigned short*)alloc((size_t)GH * HH * 2);
  unsigned short* Whh1b = (unsigned short*)alloc((size_t)GH * HH * 2);
  float* h2last = (float*)alloc((size_t)BB * HH * 4);
  unsigned short* xb = (unsigned short*)alloc((size_t)BB * TT * DD * 2);
  unsigned short* h1buf = (unsigned short*)alloc((size_t)GB * TT * ROWS * 2);
  unsigned short* hxrow = (unsigned short*)alloc((size_t)GB * 2 * 2 * ROWS * 2);
  int* claim = (int*)alloc(4096);

  if (ws_size < off) return;  // visible failure instead of corruption

  zero_claim_k<<<1, 1024, 0, stream>>>(claim);
  convert_bf16_k<<<2048, 256, 0, stream>>>(x, xb, BB * TT * DD);
  convert_bf16_k<<<512, 256, 0, stream>>>(Wih0, Wih0b, GH * DD);
  convert_bf16_k<<<512, 256, 0, stream>>>(Whh0, Whh0b, GH * HH);
  convert_bf16_k<<<512, 256, 0, stream>>>(Wih1, Wih1b, GH * HH);
  convert_bf16_k<<<512, 256, 0, stream>>>(Whh1, Whh1b, GH * HH);
  bias_sum_k<<<4, 256, 0, stream>>>(bih0, bhh0, bias0, GH);
  bias_sum_k<<<4, 256, 0, stream>>>(bih1, bhh1, bias1, GH);
  lstm_fused<<<NWG_LAUNCH, NTHREADS, 0, stream>>>(
      xb, h1buf, Wih0b, Whh0b, bias0, Wih1b, Whh1b, bias1, h2last, hxrow, claim);
  fc_k<<<1, 640, 0, stream>>>(h2last, Wfc, bfc, (float*)d_out);
}

// Round 7
// 6891.785 us; speedup vs baseline: 3.6603x; 3.6603x over previous
//
#include <hip/hip_runtime.h>
#include <stdint.h>

typedef __bf16 bf16x8 __attribute__((ext_vector_type(8)));
typedef float f32x4 __attribute__((ext_vector_type(4)));
typedef unsigned long long u64;

#define BB 64
#define TT 2048
#define DD 320
#define HH 256
#define NC 10
#define GH 1024  // 4*H

#define GB 4         // batch groups (16 batches each)
#define GJ 4         // j-slice WGs per group (64 hidden units each)
#define MB 16        // batches per group
#define JW 64        // hidden units per WG
#define NTHREADS 512 // 8 waves
#define SHS 264      // shorts stride for 16x256 bf16 LDS tiles
#define NPAIR 2048   // 128 pairs x 16 batches qwords per (group, parity)
#define NPT 4        // qx words per thread (L1 input)
#define NRW 3        // remote hx words per thread (own slice excluded)
#define NWG_LAUNCH 64
#define HSROUNDS 3
#define HSSPIN 256

__device__ __forceinline__ unsigned short f2bf(float f) {
  unsigned u = __float_as_uint(f);
  u += 0x7FFF + ((u >> 16) & 1);  // RNE
  return (unsigned short)(u >> 16);
}

__global__ void convert_bf16_k(const float* __restrict__ src,
                               unsigned short* __restrict__ dst, int n) {
  int i = blockIdx.x * blockDim.x + threadIdx.x;
  int st = gridDim.x * blockDim.x;
  for (; i < n; i += st) dst[i] = f2bf(src[i]);
}

__global__ void bias_sum_k(const float* __restrict__ a, const float* __restrict__ b,
                           float* __restrict__ d, int n) {
  int i = blockIdx.x * blockDim.x + threadIdx.x;
  if (i < n) d[i] = a[i] + b[i];
}

__global__ void zero_claim_k(int* p) { p[threadIdx.x] = 0; }

__device__ __forceinline__ float sigm(float x) { return 1.f / (1.f + __expf(-x)); }
__device__ __forceinline__ float tanh_s(float x) { return 2.f * sigm(2.f * x) - 1.f; }

__device__ __forceinline__ u64 ald(const u64* p) {
  return __hip_atomic_load(p, __ATOMIC_RELAXED, __HIP_MEMORY_SCOPE_AGENT);
}
__device__ __forceinline__ void ast(u64* p, u64 v) {
  __hip_atomic_store(p, v, __ATOMIC_RELAXED, __HIP_MEMORY_SCOPE_AGENT);
}

// ---- XCD-local (same-L2) exchange path (R5-proven) -----------------------
__device__ __forceinline__ void st_wt(u64* p, u64 v) {
  asm volatile("global_store_dwordx2 %0, %1, off" : : "v"(p), "v"(v) : "memory");
}
__device__ __forceinline__ void ld_sc0_issue(const u64* p, u64& d) {
  asm volatile("global_load_dwordx2 %0, %1, off sc0" : "=&v"(d) : "v"(p) : "memory");
}
__device__ __forceinline__ u64 ld1_sc0(const u64* p) {
  u64 v;
  asm volatile("global_load_dwordx2 %0, %1, off sc0\n\t"
               "s_waitcnt vmcnt(0)"
               : "=&v"(v) : "v"(p) : "memory");
  __builtin_amdgcn_sched_barrier(0);
  return v;
}
__device__ __forceinline__ void vm_wait0() {
  asm volatile("s_waitcnt vmcnt(0)" ::: "memory");
  __builtin_amdgcn_sched_barrier(0);  // rule #18: pin uses after the wait
}

// R7-hardware-verified in-register 4x4 transpose among each 4-lane cluster.
__device__ __forceinline__ void xpose4(f32x4& v, int ln) {
  const bool b0 = (ln & 1) != 0;
  const bool b1 = (ln & 2) != 0;
  float x0 = __shfl_xor((float)v[0], 1);
  float x1 = __shfl_xor((float)v[1], 1);
  float x2 = __shfl_xor((float)v[2], 1);
  float x3 = __shfl_xor((float)v[3], 1);
  f32x4 u;
  u[0] = b0 ? x1 : v[0];
  u[1] = b0 ? v[1] : x0;
  u[2] = b0 ? x3 : v[2];
  u[3] = b0 ? v[3] : x2;
  float y0 = __shfl_xor((float)u[0], 2);
  float y1 = __shfl_xor((float)u[1], 2);
  float y2 = __shfl_xor((float)u[2], 2);
  float y3 = __shfl_xor((float)u[3], 2);
  v[0] = b1 ? y2 : u[0];
  v[1] = b1 ? y3 : u[1];
  v[2] = b1 ? u[2] : y0;
  v[3] = b1 ? u[3] : y1;
}

// R10: persistent fused 2-layer LSTM. Tagged relaxed 8B words (2 bf16 |
// step tag) carry all cross-WG data — R0's proven protocol. Structure:
//  - gate-quad weight permute + xpose4 (R7-verified): no sG, no B2; ONE
//    barrier per step with parity-double-buffered sX/sH.
//  - PAIR-MAJOR exchange layout [pair][batch]: R7's compute layout then
//    publishes 4x128B contiguous segments per wave (fixes R7's scatter
//    regression: +100MB retry FETCH, +4000cy/step).
//  - qh exchange words prefetched at END of step t (right after our own
//    publish) — flight absorbed by the loop tail instead of serializing
//    at the top of step t+1.
template <int KCX, bool IS_L0>
__device__ __forceinline__ void lstm_role(
    const unsigned short* __restrict__ xin,  // L0: x bf16 [B][T][KCX*32]
    u64* __restrict__ h1g,                   // tagged h1, pair-major [TT][128][16]
    const unsigned short* __restrict__ Wih,
    const unsigned short* __restrict__ Whh,
    const float* __restrict__ bias,
    float* __restrict__ hlast,               // L1: [B][HH] f32
    u64* __restrict__ hx,                    // [GB][2][128][16]
    unsigned short* sX0, unsigned short* sX1,
    unsigned short* sH0, unsigned short* sH1,
    int gb, int gj, bool local)
{
  constexpr int KX = KCX * 32;
  constexpr int KCH = HH / 32;  // 8

  const int tid = threadIdx.x;
  const int wv = tid >> 6;
  const int ln = tid & 63;
  const int lm = ln & 15;
  const int lq = ln >> 4;
  const int j0 = gj * JW;
  const int b0 = gb * MB;

  // ---- weights -> registers (once), gate-quad permuted rows (R7) ----
  bf16x8 bW[2][KCX + KCH];
  float bsv[2];
#pragma unroll
  for (int i = 0; i < 2; ++i) {
    int grow = (lm & 3) * HH + j0 + wv * 8 + ((lm >> 2) << 1) + i;
#pragma unroll
    for (int kc = 0; kc < KCX; ++kc)
      bW[i][kc] = *(const bf16x8*)&Wih[(size_t)grow * KX + kc * 32 + lq * 8];
#pragma unroll
    for (int kc = 0; kc < KCH; ++kc)
      bW[i][KCX + kc] = *(const bf16x8*)&Whh[(size_t)grow * HH + kc * 32 + lq * 8];
    bsv[i] = bias[grow];
  }

  // ---- remote hx word ids, pair-major (3/thread, own 32-pair slice
  //      excluded). 16 consecutive threads share a pair -> 128B segments.
  int rw[NRW];
#pragma unroll
  for (int i = 0; i < NRW; ++i) {
    int rp = i * NTHREADS + tid;   // 0..1535
    int pr = rp >> 4;              // remote-pair rank 0..95
    int b  = rp & 15;
    int pe = pr >> 5;
    pe += (pe >= gj);              // skip own peer slot
    rw[i] = (pe * 32 + (pr & 31)) * 16 + b;   // word = p*16 + b
  }

  u64* const hxg = hx + (size_t)gb * 2 * NPAIR;

  // Output cell assignment from the transposed quad (R7-verified):
  const int pbatch = lq * 4 + (lm & 3);            // batch in group 0..15
  const int p_own  = (j0 >> 1) + wv * 4 + (lm >> 2); // global pair 0..127
  const int uoff   = 2 * p_own - j0 + j0;          // = j0 + wv*8 + 2*(lm>>2)
  float c0 = 0.f, c1 = 0.f;

  // ---- preamble prefetch for t=0 ----
  bf16x8 xf[IS_L0 ? KCX : 1];
  u64 qx[NPT];
  u64 qh[NRW];
  if (IS_L0) {
#pragma unroll
    for (int kc = 0; kc < KCX; ++kc)
      xf[kc] = *(const bf16x8*)&xin[((size_t)(b0 + lm) * TT + 0) * KX + kc * 32 + lq * 8];
  } else {
#pragma unroll
    for (int i = 0; i < NPT; ++i) {
      int w = i * NTHREADS + tid;   // word = p*16 + b
      const u64* p = &h1g[(size_t)0 * NPAIR + w];
      if (local) ld_sc0_issue(p, qx[i]); else qx[i] = ald(p);
    }
  }

  __syncthreads();

#pragma unroll 1
  for (int t = 0; t < TT; ++t) {
    const int par = t & 1;
    unsigned short* const sXc = par ? sX1 : sX0;
    unsigned short* const sHc = par ? sH1 : sH0;
    unsigned short* const sHn = par ? sH0 : sH1;
    unsigned* const sXcu = (unsigned*)sXc;
    unsigned* const sHcu = (unsigned*)sHc;
    unsigned* const sHnu = (unsigned*)sHn;

    u64* const rb = hxg + (size_t)((t + 1) & 1) * NPAIR;  // slot (t-1)&1

    f32x4 ac[2][2] = {{{0.f, 0.f, 0.f, 0.f}, {0.f, 0.f, 0.f, 0.f}},
                      {{0.f, 0.f, 0.f, 0.f}, {0.f, 0.f, 0.f, 0.f}}};
    if (IS_L0) {
      // x-part from prefetched regs — fills the exchange-wait window
#pragma unroll
      for (int kc = 0; kc < KCX; ++kc) {
        ac[0][kc & 1] = __builtin_amdgcn_mfma_f32_16x16x32_bf16(xf[kc], bW[0][kc], ac[0][kc & 1], 0, 0, 0);
        ac[1][kc & 1] = __builtin_amdgcn_mfma_f32_16x16x32_bf16(xf[kc], bW[1][kc], ac[1][kc & 1], 0, 0, 0);
      }
    }
    if (local) vm_wait0();  // prefetched qh (end of t-1) / qx now resident

    // ---- spin (reload only the failing stream); qh/qx were prefetched ----
    {
      const unsigned etx = (unsigned)(t + 1), eth = (unsigned)t;
      bool ok;
      do {
        bool okx = true, okh = true;
        if (!IS_L0) {
#pragma unroll
          for (int i = 0; i < NPT; ++i) okx &= ((unsigned)(qx[i] >> 32) == etx);
        }
        if (t > 0) {
#pragma unroll
          for (int i = 0; i < NRW; ++i) okh &= ((unsigned)(qh[i] >> 32) == eth);
        }
        ok = okx && okh;
        if (!ok) {
          if (!IS_L0 && !okx) {
#pragma unroll
            for (int i = 0; i < NPT; ++i) {
              int w = i * NTHREADS + tid;
              const u64* p = &h1g[(size_t)t * NPAIR + w];
              if (local) ld_sc0_issue(p, qx[i]); else qx[i] = ald(p);
            }
          }
          if (t > 0 && !okh) {
#pragma unroll
            for (int i = 0; i < NRW; ++i) {
              const u64* p = &rb[rw[i]];
              if (local) ld_sc0_issue(p, qh[i]); else qh[i] = ald(p);
            }
          }
          if (local) vm_wait0();
        }
      } while (!ok);
    }

    // ---- stage to LDS parity buffers (word p*16+b -> sU[b*132 + p]) ----
    if (!IS_L0) {
#pragma unroll
      for (int i = 0; i < NPT; ++i) {
        int w = i * NTHREADS + tid;
        sXcu[(w & 15) * (SHS / 2) + (w >> 4)] = (unsigned)qx[i];
      }
    }
    if (t > 0) {
#pragma unroll
      for (int i = 0; i < NRW; ++i)
        sHcu[(rw[i] & 15) * (SHS / 2) + (rw[i] >> 4)] = (unsigned)qh[i];
    }
    __syncthreads();  // B1 — the only barrier per step

    // ---- prefetch inputs for t+1 (overlaps MFMA + elementwise) ----
    if (t + 1 < TT) {
      if (IS_L0) {
#pragma unroll
        for (int kc = 0; kc < KCX; ++kc)
          xf[kc] = *(const bf16x8*)&xin[((size_t)(b0 + lm) * TT + (t + 1)) * KX + kc * 32 + lq * 8];
      } else {
#pragma unroll
        for (int i = 0; i < NPT; ++i) {
          int w = i * NTHREADS + tid;
          const u64* p = &h1g[(size_t)(t + 1) * NPAIR + w];
          if (local) ld_sc0_issue(p, qx[i]); else qx[i] = ald(p);
        }
      }
    }

    if (!IS_L0) {
#pragma unroll
      for (int kc = 0; kc < KCX; ++kc) {
        bf16x8 a = *(const bf16x8*)&sXc[lm * SHS + kc * 32 + lq * 8];
        ac[0][kc & 1] = __builtin_amdgcn_mfma_f32_16x16x32_bf16(a, bW[0][kc], ac[0][kc & 1], 0, 0, 0);
        ac[1][kc & 1] = __builtin_amdgcn_mfma_f32_16x16x32_bf16(a, bW[1][kc], ac[1][kc & 1], 0, 0, 0);
      }
    }
    if (t > 0) {
#pragma unroll
      for (int kc = 0; kc < KCH; ++kc) {
        bf16x8 a = *(const bf16x8*)&sHc[lm * SHS + kc * 32 + lq * 8];
        ac[0][kc & 1] = __builtin_amdgcn_mfma_f32_16x16x32_bf16(a, bW[0][KCX + kc], ac[0][kc & 1], 0, 0, 0);
        ac[1][kc & 1] = __builtin_amdgcn_mfma_f32_16x16x32_bf16(a, bW[1][KCX + kc], ac[1][kc & 1], 0, 0, 0);
      }
    }

    // ---- gate quad regroup in-register (R7-verified) ----
    f32x4 A0 = ac[0][0] + ac[0][1];
    f32x4 A1 = ac[1][0] + ac[1][1];
    A0[0] += bsv[0]; A0[1] += bsv[0]; A0[2] += bsv[0]; A0[3] += bsv[0];
    A1[0] += bsv[1]; A1[1] += bsv[1]; A1[2] += bsv[1]; A1[3] += bsv[1];
    xpose4(A0, ln);  // slots = i,f,g,o of unit uoff   for batch pbatch
    xpose4(A1, ln);  // slots = i,f,g,o of unit uoff+1

    c0 = sigm(A0[1]) * c0 + sigm(A0[0]) * tanh_s(A0[2]);
    c1 = sigm(A1[1]) * c1 + sigm(A1[0]) * tanh_s(A1[2]);
    float h0 = sigm(A0[3]) * tanh_s(c0);
    float h1 = sigm(A1[3]) * tanh_s(c1);
    unsigned pair = (unsigned)f2bf(h0) | ((unsigned)f2bf(h1) << 16);
    u64 val = ((u64)(unsigned)(t + 1) << 32) | pair;

    // ---- publish (pair-major: 4x128B contiguous per wave), then sHn ----
    u64* pw = &hxg[(size_t)par * NPAIR + p_own * 16 + pbatch];
    if (local) st_wt(pw, val); else ast(pw, val);
    if (IS_L0) {
      u64* po = &h1g[(size_t)t * NPAIR + p_own * 16 + pbatch];
      if (local) st_wt(po, val); else ast(po, val);
    } else if (t == TT - 1) {
      hlast[(size_t)(b0 + pbatch) * HH + uoff] = h0;
      hlast[(size_t)(b0 + pbatch) * HH + uoff + 1] = h1;
    }
    sHnu[pbatch * (SHS / 2) + p_own] = pair;  // own slice, next parity

    // ---- EARLY qh prefetch for t+1 (flight absorbed by loop tail) ----
    if (t + 1 < TT) {
      u64* const rbn = hxg + (size_t)par * NPAIR;
#pragma unroll
      for (int i = 0; i < NRW; ++i) {
        const u64* p = &rbn[rw[i]];
        if (local) ld_sc0_issue(p, qh[i]); else qh[i] = ald(p);
      }
    }
  }
}

__launch_bounds__(NTHREADS, 1)
__global__ void lstm_fused(const unsigned short* __restrict__ xb,
                           u64* __restrict__ h1buf,
                           const unsigned short* __restrict__ Wih0,
                           const unsigned short* __restrict__ Whh0,
                           const float* __restrict__ bias0,
                           const unsigned short* __restrict__ Wih1,
                           const unsigned short* __restrict__ Whh1,
                           const float* __restrict__ bias1,
                           float* __restrict__ h2last,
                           u64* __restrict__ hx0, u64* __restrict__ hx1,
                           int* __restrict__ claim) {
  __shared__ __align__(16) unsigned short sX[2][MB * SHS];
  __shared__ __align__(16) unsigned short sH[2][MB * SHS];
  __shared__ int sCtl[2];

  const int gb = (int)blockIdx.x & 7;
  const int sub = (int)blockIdx.x >> 3;
  if (gb >= GB) return;

  if (threadIdx.x == 0) {
    u64* hs = (u64*)claim;                   // [32] tokens
    unsigned* vd = (unsigned*)(claim + 64);  // [32] verdicts
    const int gid = gb * 8 + sub;
    bool lok = true;
    for (int r = 0; r < HSROUNDS && lok; ++r) {
      st_wt(&hs[gid], ((u64)(0xC0DE0000u + (unsigned)r) << 32) | (unsigned)gid);
      int it = 0;
      bool all;
      do {
        all = true;
        for (int m = 0; m < 8; ++m) {
          u64 v = ld1_sc0(&hs[gb * 8 + m]);
          unsigned hv = (unsigned)(v >> 32) - 0xC0DE0000u;
          all &= (hv >= (unsigned)r && hv < (unsigned)HSROUNDS);
        }
      } while (!all && ++it < HSSPIN);
      lok &= all;
    }
    __hip_atomic_store(&vd[gid], lok ? 2u : 1u, __ATOMIC_RELAXED,
                       __HIP_MEMORY_SCOPE_AGENT);
    bool ul = true;
    for (int m = 0; m < 8; ++m) {
      unsigned v;
      do {
        v = __hip_atomic_load(&vd[gb * 8 + m], __ATOMIC_RELAXED,
                              __HIP_MEMORY_SCOPE_AGENT);
      } while (v == 0);
      ul &= (v == 2);
    }
    sCtl[0] = ul ? 1 : 0;
  }
  __syncthreads();
  const bool local = sCtl[0] != 0;

  const int role = sub >> 2;
  const int gj = sub & 3;
  u64* h1g = h1buf + (size_t)gb * TT * NPAIR;
  if (role == 0)
    lstm_role<DD / 32, true>(xb, h1g, Wih0, Whh0, bias0, nullptr,
                             hx0, sX[0], sX[1], sH[0], sH[1], gb, gj, local);
  else
    lstm_role<HH / 32, false>(nullptr, h1g, Wih1, Whh1, bias1, h2last,
                              hx1, sX[0], sX[1], sH[0], sH[1], gb, gj, local);
}

__global__ void fc_k(const float* __restrict__ h, const float* __restrict__ W,
                     const float* __restrict__ b, float* __restrict__ out) {
  int tid = threadIdx.x;
  if (tid < BB * NC) {
    int bb = tid / NC, cc = tid % NC;
    float s = b[cc];
    for (int j = 0; j < HH; ++j) s += h[bb * HH + j] * W[cc * HH + j];
    out[tid] = s;
  }
}

extern "C" void kernel_launch(void* const* d_in, const int* in_sizes, int n_in,
                              void* d_out, int out_size, void* d_ws, size_t ws_size,
                              hipStream_t stream) {
  (void)in_sizes; (void)n_in; (void)out_size;
  const float* x    = (const float*)d_in[0];
  const float* Wih0 = (const float*)d_in[1];
  const float* Whh0 = (const float*)d_in[2];
  const float* bih0 = (const float*)d_in[3];
  const float* bhh0 = (const float*)d_in[4];
  const float* Wih1 = (const float*)d_in[5];
  const float* Whh1 = (const float*)d_in[6];
  const float* bih1 = (const float*)d_in[7];
  const float* bhh1 = (const float*)d_in[8];
  const float* Wfc  = (const float*)d_in[9];
  const float* bfc  = (const float*)d_in[10];

  char* p = (char*)d_ws;
  size_t off = 0;
  auto alloc = [&](size_t bytes) -> char* {
    char* q = p + off;
    off += (bytes + 255) & ~(size_t)255;
    return q;
  };
  u64* hx0 = (u64*)alloc((size_t)GB * 2 * NPAIR * 8);
  u64* hx1 = (u64*)alloc((size_t)GB * 2 * NPAIR * 8);
  float* bias0 = (float*)alloc(GH * 4);
  float* bias1 = (float*)alloc(GH * 4);
  unsigned short* Wih0b = (unsigned short*)alloc((size_t)GH * DD * 2);
  unsigned short* Whh0b = (unsigned short*)alloc((size_t)GH * HH * 2);
  unsigned short* Wih1b = (unsigned short*)alloc((size_t)GH * HH * 2);
  unsigned short* Whh1b = (unsigned short*)alloc((size_t)GH * HH * 2);
  float* h2last = (float*)alloc((size_t)BB * HH * 4);
  unsigned short* xb = (unsigned short*)alloc((size_t)BB * TT * DD * 2);
  u64* h1buf = (u64*)alloc((size_t)GB * TT * NPAIR * 8);
  int* claim = (int*)alloc(1024);

  if (ws_size < off) return;  // visible failure instead of corruption

  zero_claim_k<<<1, 256, 0, stream>>>(claim);
  convert_bf16_k<<<2048, 256, 0, stream>>>(x, xb, BB * TT * DD);
  convert_bf16_k<<<512, 256, 0, stream>>>(Wih0, Wih0b, GH * DD);
  convert_bf16_k<<<512, 256, 0, stream>>>(Whh0, Whh0b, GH * HH);
  convert_bf16_k<<<512, 256, 0, stream>>>(Wih1, Wih1b, GH * HH);
  convert_bf16_k<<<512, 256, 0, stream>>>(Whh1, Whh1b, GH * HH);
  bias_sum_k<<<4, 256, 0, stream>>>(bih0, bhh0, bias0, GH);
  bias_sum_k<<<4, 256, 0, stream>>>(bih1, bhh1, bias1, GH);
  lstm_fused<<<NWG_LAUNCH, NTHREADS, 0, stream>>>(
      xb, h1buf, Wih0b, Whh0b, bias0, Wih1b, Whh1b, bias1, h2last, hx0, hx1, claim);
  fc_k<<<1, 640, 0, stream>>>(h2last, Wfc, bfc, (float*)d_out);
}